// Round 12
// baseline (38.024 us; speedup 1.0000x reference)
//
#include <hip/hip_runtime.h>

#define NL 5

typedef float v2f __attribute__((ext_vector_type(2)));

// flip sign of v iff bit==1
__device__ __forceinline__ float sflip(float v, unsigned bit) {
    return __uint_as_float(__float_as_uint(v) ^ (bit << 31));
}

// ---- packed FP32 complex helpers (VOP3P, 2 FLOP/lane/instr) ----
// RX butterfly: new = (c*me.x + s*o.y, c*me.y - s*o.x), sc = (s, c)
__device__ __forceinline__ v2f rotg_pk(v2f me, v2f o, v2f sc) {
    v2f t, r;
    // t.lo = s*o.hi ; t.hi = -s*o.lo
    asm("v_pk_mul_f32 %0, %1, %2 op_sel:[0,1] op_sel_hi:[0,0] neg_hi:[1,0]"
        : "=v"(t) : "v"(sc), "v"(o));
    // r.lo = c*me.lo + t.lo ; r.hi = c*me.hi + t.hi
    asm("v_pk_fma_f32 %0, %1, %2, %3 op_sel:[1,0,0] op_sel_hi:[1,1,1]"
        : "=v"(r) : "v"(sc), "v"(me), "v"(t));
    return r;
}
// complex phase: new = (x*cs - y*sn, x*sn + y*cs), sc = (sn, cs)
__device__ __forceinline__ v2f cmul_pk(v2f a, v2f sc) {
    v2f t, r;
    // t.lo = -sn*a.hi ; t.hi = sn*a.lo
    asm("v_pk_mul_f32 %0, %1, %2 op_sel:[0,1] op_sel_hi:[0,0] neg_lo:[1,0]"
        : "=v"(t) : "v"(sc), "v"(a));
    // r.lo = cs*a.lo + t.lo ; r.hi = cs*a.hi + t.hi
    asm("v_pk_fma_f32 %0, %1, %2, %3 op_sel:[1,0,0] op_sel_hi:[1,1,1]"
        : "=v"(r) : "v"(sc), "v"(a), "v"(t));
    return r;
}

// DPP cross-lane on the VALU pipe.
//   0xB1 = quad_perm [1,0,3,2]  -> lane^1
//   0x4E = quad_perm [2,3,0,1]  -> lane^2
//   0x1B = quad_perm [3,2,1,0]  -> lane^3
//   0x141 = row_half_mirror     -> lane^7 (within 8)
//   0x128 = row_ror:8           -> lane^8 (xor 8 within a 16-row)
template <int CTRL>
__device__ __forceinline__ float dppx(float v) {
    return __int_as_float(__builtin_amdgcn_update_dpp(
        0, __float_as_int(v), CTRL, 0xF, 0xF, true));
}
// data from lane^4 = (^7) then (^3)
__device__ __forceinline__ float dpp_x4(float v) { return dppx<0x1B>(dppx<0x141>(v)); }

// ---- permlane pair-swap (inline asm, "+v" tied in/out) ----
// After the swap each lane holds both xor-MASK partners of one logical
// register -> butterfly is lane-local; swap again to restore. (HW-verified
// correct in R11: absmax 6.1e-5.)
template <bool IS32>
__device__ __forceinline__ void swap_pair(float &X, float &Y) {
    if (IS32)
        asm("v_permlane32_swap_b32 %0, %1" : "+v"(X), "+v"(Y));
    else
        asm("v_permlane16_swap_b32 %0, %1" : "+v"(X), "+v"(Y));
}
// RX gate for lane-mask 32 (IS32) or 16 on a register pair (A,B)
template <bool IS32>
__device__ __forceinline__ void gate_pl(v2f &A, v2f &B, v2f sc) {
    float ax = A.x, ay = A.y, bx = B.x, by = B.y;
    swap_pair<IS32>(ax, bx);
    swap_pair<IS32>(ay, by);
    const v2f u = {ax, ay}, v = {bx, by};
    v2f nu = rotg_pk(u, v, sc);
    v2f nv = rotg_pk(v, u, sc);
    ax = nu.x; ay = nu.y; bx = nv.x; by = nv.y;
    swap_pair<IS32>(ax, bx);
    swap_pair<IS32>(ay, by);
    A = (v2f){ax, ay};
    B = (v2f){bx, by};
}

// all-lanes butterfly sum across the 64-lane wave (one-shot, DS ok)
__device__ __forceinline__ float wave_sum(float v) {
    v += dppx<0xB1>(v);
    v += dppx<0x4E>(v);
    v += dpp_x4(v);
    v += dppx<0x128>(v);
    v += __shfl_xor(v, 16);
    v += __shfl_xor(v, 32);
    return v;
}

__global__ __launch_bounds__(128, 8)
void ppo_quantum_kernel(const float* __restrict__ x,        // (B,55)
                        const float* __restrict__ isa,      // (5,)
                        const float* __restrict__ wa,       // (5,)
                        const float* __restrict__ osa,      // (10,)
                        const float* __restrict__ isc,      // (5,)
                        const float* __restrict__ wc,       // (5,)
                        const float* __restrict__ osc,      // (1,)
                        const int*   __restrict__ action,   // (B,)
                        float* __restrict__ out)            // (B,3)
{
    const int t    = threadIdx.x;      // 128 threads = 2 waves (one circuit)
    const int w    = t >> 6;           // wave bit = amplitude bit d9 (qubit 0)
    const int lane = t & 63;           // lane bits = d5..d0 (qubits 4..9)
    const int elem = blockIdx.x >> 1;
    const int circ = blockIdx.x & 1;   // 0 = actor, 1 = critic
    const float* __restrict__ xr = x + elem * 55;   // uniform -> scalar loads

    __shared__ v2f   xch[8][128];      // 8 KB exchange for the qubit-0 gate
    __shared__ float red[2][10];

    // amplitude d = (w<<9) | (r<<6) | lane, r = 0..7 (bits d8..d6 = qubits 1..3)
    unsigned lb[6];                    // lane bit of qubit 4+k
#pragma unroll
    for (int k = 0; k < 6; ++k) lb[k] = (lane >> (5 - k)) & 1u;

    // ---- expo decomposition ----
    float L = 0.f;                     // lane-only: singles 4..9 + pairs among them
#pragma unroll
    for (int k = 0; k < 6; ++k) L += sflip(xr[4 + k], lb[k]);
    {
        int p = 40;                    // J_ij for i,j in 4..9 at x[40..54]
#pragma unroll
        for (int i = 0; i < 6; ++i)
#pragma unroll
            for (int j = i + 1; j < 6; ++j)
                L += sflip(xr[p++], lb[i] ^ lb[j]);
    }
    float T0 = xr[0], T1 = xr[1], T2 = xr[2], T3 = xr[3];
#pragma unroll
    for (int k = 0; k < 6; ++k) {      // cross terms J_{i,4..9}
        T0 += sflip(xr[13 + k], lb[k]);
        T1 += sflip(xr[21 + k], lb[k]);
        T2 += sflip(xr[28 + k], lb[k]);
        T3 += sflip(xr[34 + k], lb[k]);
    }
    const unsigned uw = (unsigned)w;
    T0 = sflip(T0, uw);                // fold wave bit (z_0) into T0 and J_0x
    const float J01 = sflip(xr[10], uw), J02 = sflip(xr[11], uw), J03 = sflip(xr[12], uw);
    const float J12 = xr[19], J13 = xr[20], J23 = xr[27];

    float expo[8];
#pragma unroll
    for (int r = 0; r < 8; ++r) {
        const unsigned b1 = (r >> 2) & 1u, b2 = (r >> 1) & 1u, b3 = r & 1u;
        float e = L + T0;
        e += sflip(T1, b1);      e += sflip(T2, b2);      e += sflip(T3, b3);
        e += sflip(J01, b1);     e += sflip(J02, b2);     e += sflip(J03, b3);
        e += sflip(J12, b1 ^ b2); e += sflip(J13, b1 ^ b3); e += sflip(J23, b2 ^ b3);
        expo[r] = e;
    }

    // ---- simulate this block's circuit ----
    const float* iscale = circ ? isc : isa;
    const float* wts    = circ ? wc  : wa;

    v2f a[8];
#pragma unroll
    for (int r = 0; r < 8; ++r) a[r] = (v2f){0.03125f, 0.f};  // 1/sqrt(1024)

#pragma unroll 1
    for (int l = 0; l < NL; ++l) {
        const float m = -0.5f * iscale[l];
        float c, s;
        __sincosf(0.5f * wts[l], &s, &c);
        const v2f sc = {s, c};

        // diagonal phase (packed complex mul)
#pragma unroll
        for (int r = 0; r < 8; ++r) {
            float sn, cs;
            __sincosf(m * expo[r], &sn, &cs);
            const v2f ph = {sn, cs};
            a[r] = cmul_pk(a[r], ph);
        }

        // qubits 1..3: register butterflies (r-bit masks 4,2,1)
#pragma unroll
        for (int g = 0; g < 3; ++g) {
            const int qm = 4 >> g;
#pragma unroll
            for (int r = 0; r < 8; ++r)
                if (!(r & qm)) {
                    const v2f lo = a[r], hi = a[r | qm];
                    a[r]      = rotg_pk(lo, hi, sc);
                    a[r | qm] = rotg_pk(hi, lo, sc);
                }
        }

        // qubit 4: lane^32 via paired permlane32_swap (VALU, no DS)
#pragma unroll
        for (int r = 0; r < 8; r += 2) gate_pl<true>(a[r], a[r + 1], sc);
        // qubit 5: lane^16 via paired permlane16_swap (VALU, no DS)
#pragma unroll
        for (int r = 0; r < 8; r += 2) gate_pl<false>(a[r], a[r + 1], sc);

        // qubit 6: lane^8 via DPP row_ror:8
#pragma unroll
        for (int r = 0; r < 8; ++r) {
            const v2f o = {dppx<0x128>(a[r].x), dppx<0x128>(a[r].y)};
            a[r] = rotg_pk(a[r], o, sc);
        }
        // qubit 7: lane^4 via composed DPP (^7 then ^3)
#pragma unroll
        for (int r = 0; r < 8; ++r) {
            const v2f o = {dpp_x4(a[r].x), dpp_x4(a[r].y)};
            a[r] = rotg_pk(a[r], o, sc);
        }
        // qubit 8: lane^2 via quad_perm
#pragma unroll
        for (int r = 0; r < 8; ++r) {
            const v2f o = {dppx<0x4E>(a[r].x), dppx<0x4E>(a[r].y)};
            a[r] = rotg_pk(a[r], o, sc);
        }
        // qubit 9: lane^1 via quad_perm
#pragma unroll
        for (int r = 0; r < 8; ++r) {
            const v2f o = {dppx<0xB1>(a[r].x), dppx<0xB1>(a[r].y)};
            a[r] = rotg_pk(a[r], o, sc);
        }

        // qubit 0 (wave bit): LDS exchange, applied last (gates commute)
        __syncthreads();                       // prior reads of xch done
#pragma unroll
        for (int r = 0; r < 8; ++r) xch[r][t] = a[r];
        __syncthreads();
#pragma unroll
        for (int r = 0; r < 8; ++r) {
            const v2f o = xch[r][t ^ 64];
            a[r] = rotg_pk(a[r], o, sc);
        }
    }

    // ---- probabilities & expectation values ----
    float p[8];
#pragma unroll
    for (int r = 0; r < 8; ++r) p[r] = a[r].x * a[r].x + a[r].y * a[r].y;
    float tot = 0.f;
#pragma unroll
    for (int r = 0; r < 8; ++r) tot += p[r];

    if (circ == 0) {
        float v[10];
        v[0] = sflip(tot, uw);                                            // qubit 0
        v[1] = (p[0] + p[1] + p[2] + p[3]) - (p[4] + p[5] + p[6] + p[7]); // r bit 2
        v[2] = (p[0] + p[1] + p[4] + p[5]) - (p[2] + p[3] + p[6] + p[7]); // r bit 1
        v[3] = (p[0] + p[2] + p[4] + p[6]) - (p[1] + p[3] + p[5] + p[7]); // r bit 0
#pragma unroll
        for (int k = 0; k < 6; ++k) v[4 + k] = sflip(tot, lb[k]);

#pragma unroll
        for (int q = 0; q < 10; ++q) v[q] = wave_sum(v[q]);

        if (lane == 0)
#pragma unroll
            for (int q = 0; q < 10; ++q) red[w][q] = v[q];
        __syncthreads();

        // epilogue redundantly on all threads, thread 0 stores
        float logits[10], mx = -1e30f;
#pragma unroll
        for (int q = 0; q < 10; ++q) {
            logits[q] = (red[0][q] + red[1][q]) * osa[q];
            mx = fmaxf(mx, logits[q]);
        }
        float se = 0.f;
#pragma unroll
        for (int q = 0; q < 10; ++q) se += __expf(logits[q] - mx);
        const float lse = __logf(se) + mx;
        float ent = 0.f;
#pragma unroll
        for (int q = 0; q < 10; ++q) {
            const float lp = logits[q] - lse;
            ent -= __expf(lp) * lp;
        }
        if (t == 0) {
            const int act = action[elem];
            out[elem * 3 + 0] = logits[act] - lse;
            out[elem * 3 + 1] = ent;
        }
    } else {
        float v0 = sflip(tot, uw);
        v0 = wave_sum(v0);
        if (lane == 0) red[w][0] = v0;
        __syncthreads();
        if (t == 0) out[elem * 3 + 2] = (red[0][0] + red[1][0]) * osc[0];
    }
}

extern "C" void kernel_launch(void* const* d_in, const int* in_sizes, int n_in,
                              void* d_out, int out_size, void* d_ws, size_t ws_size,
                              hipStream_t stream) {
    const float* x      = (const float*)d_in[0];
    const float* isa    = (const float*)d_in[1];
    const float* wa     = (const float*)d_in[2];
    const float* osa    = (const float*)d_in[3];
    const float* isc    = (const float*)d_in[4];
    const float* wc     = (const float*)d_in[5];
    const float* osc    = (const float*)d_in[6];
    const int*   action = (const int*)d_in[7];
    float*       out    = (float*)d_out;

    const int B = in_sizes[7];
    // one (elem, circuit) per 128-thread block -> 2*B blocks = 8192 waves
    ppo_quantum_kernel<<<B * 2, 128, 0, stream>>>(x, isa, wa, osa, isc, wc, osc,
                                                  action, out);
}

// Round 14
// 36.276 us; speedup vs baseline: 1.0482x; 1.0482x over previous
//
#include <hip/hip_runtime.h>

#define NL 5

typedef float v2f __attribute__((ext_vector_type(2)));

// flip sign of v iff bit==1
__device__ __forceinline__ float sflip(float v, unsigned bit) {
    return __uint_as_float(__float_as_uint(v) ^ (bit << 31));
}

// ---- packed FP32 complex helpers (VOP3P, 2 FLOP/lane/instr) ----
// RX butterfly: new = (c*me.x + s*o.y, c*me.y - s*o.x), sc = (s, c)
__device__ __forceinline__ v2f rotg_pk(v2f me, v2f o, v2f sc) {
    v2f t, r;
    // t.lo = s*o.hi ; t.hi = -s*o.lo
    asm("v_pk_mul_f32 %0, %1, %2 op_sel:[0,1] op_sel_hi:[0,0] neg_hi:[1,0]"
        : "=v"(t) : "v"(sc), "v"(o));
    // r.lo = c*me.lo + t.lo ; r.hi = c*me.hi + t.hi
    asm("v_pk_fma_f32 %0, %1, %2, %3 op_sel:[1,0,0] op_sel_hi:[1,1,1]"
        : "=v"(r) : "v"(sc), "v"(me), "v"(t));
    return r;
}
// complex phase: new = (x*cs - y*sn, x*sn + y*cs), sc = (sn, cs)
__device__ __forceinline__ v2f cmul_pk(v2f a, v2f sc) {
    v2f t, r;
    // t.lo = -sn*a.hi ; t.hi = sn*a.lo
    asm("v_pk_mul_f32 %0, %1, %2 op_sel:[0,1] op_sel_hi:[0,0] neg_lo:[1,0]"
        : "=v"(t) : "v"(sc), "v"(a));
    // r.lo = cs*a.lo + t.lo ; r.hi = cs*a.hi + t.hi
    asm("v_pk_fma_f32 %0, %1, %2, %3 op_sel:[1,0,0] op_sel_hi:[1,1,1]"
        : "=v"(r) : "v"(sc), "v"(a), "v"(t));
    return r;
}

// DPP cross-lane on the VALU pipe.
//   0xB1 = quad_perm [1,0,3,2]  -> lane^1
//   0x4E = quad_perm [2,3,0,1]  -> lane^2
//   0x1B = quad_perm [3,2,1,0]  -> lane^3
//   0x141 = row_half_mirror     -> lane^7 (within 8)
//   0x128 = row_ror:8           -> lane^8 (xor 8 within a 16-row)
template <int CTRL>
__device__ __forceinline__ float dppx(float v) {
    return __int_as_float(__builtin_amdgcn_update_dpp(
        0, __float_as_int(v), CTRL, 0xF, 0xF, true));
}
// data from lane^4 = (^7) then (^3)
__device__ __forceinline__ float dpp_x4(float v) { return dppx<0x1B>(dppx<0x141>(v)); }

// ---- permlane pair-swap (inline asm, "+v" tied in/out) ----
// After the swap each lane holds both xor-MASK partners of one logical
// register -> butterfly is lane-local; swap again to restore. (HW-verified
// correct in R11: absmax 6.1e-5.)
template <bool IS32>
__device__ __forceinline__ void swap_pair(float &X, float &Y) {
    if (IS32)
        asm("v_permlane32_swap_b32 %0, %1" : "+v"(X), "+v"(Y));
    else
        asm("v_permlane16_swap_b32 %0, %1" : "+v"(X), "+v"(Y));
}
// RX gate for lane-mask 32 (IS32) or 16 on a register pair (A,B)
template <bool IS32>
__device__ __forceinline__ void gate_pl(v2f &A, v2f &B, v2f sc) {
    float ax = A.x, ay = A.y, bx = B.x, by = B.y;
    swap_pair<IS32>(ax, bx);
    swap_pair<IS32>(ay, by);
    const v2f u = {ax, ay}, v = {bx, by};
    v2f nu = rotg_pk(u, v, sc);
    v2f nv = rotg_pk(v, u, sc);
    ax = nu.x; ay = nu.y; bx = nv.x; by = nv.y;
    swap_pair<IS32>(ax, bx);
    swap_pair<IS32>(ay, by);
    A = (v2f){ax, ay};
    B = (v2f){bx, by};
}

// all-lanes butterfly sum across the 64-lane wave (one-shot)
__device__ __forceinline__ float wave_sum(float v) {
    v += dppx<0xB1>(v);
    v += dppx<0x4E>(v);
    v += dpp_x4(v);
    v += dppx<0x128>(v);
    v += __shfl_xor(v, 16);
    v += __shfl_xor(v, 32);
    return v;
}

__global__ __launch_bounds__(128, 2)
void ppo_quantum_kernel(const float* __restrict__ x,        // (B,55)
                        const float* __restrict__ isa,      // (5,)
                        const float* __restrict__ wa,       // (5,)
                        const float* __restrict__ osa,      // (10,)
                        const float* __restrict__ isc,      // (5,)
                        const float* __restrict__ wc,       // (5,)
                        const float* __restrict__ osc,      // (1,)
                        const int*   __restrict__ action,   // (B,)
                        float* __restrict__ out)            // (B,3)
{
    const int t    = threadIdx.x;      // 128 threads = 2 INDEPENDENT waves
    const int w    = t >> 6;           // wave -> which element of this block
    const int lane = t & 63;
    const int elem = blockIdx.x * 2 + w;
    const float* __restrict__ xr = x + elem * 55;   // wave-uniform -> scalar loads

    // amplitude index d = (r<<6) | lane, r = 0..15
    // qubit q acts on d-bit (9-q): q0..q3 -> r bits 3..0 (register gates)
    //                              q4..q9 -> lane bits 5..0 (masks 32,16,8,4,2,1)
    unsigned lb[6];                    // lane bit of qubit 4+k
#pragma unroll
    for (int k = 0; k < 6; ++k) lb[k] = (lane >> (5 - k)) & 1u;

    // ---- expo decomposition (shared by actor AND critic) ----
    float L = 0.f;                     // lane-only: singles 4..9 + pairs among them
#pragma unroll
    for (int k = 0; k < 6; ++k) L += sflip(xr[4 + k], lb[k]);
    {
        int p = 40;                    // J_ij for i,j in 4..9 at x[40..54]
#pragma unroll
        for (int i = 0; i < 6; ++i)
#pragma unroll
            for (int j = i + 1; j < 6; ++j)
                L += sflip(xr[p++], lb[i] ^ lb[j]);
    }
    float T0 = xr[0], T1 = xr[1], T2 = xr[2], T3 = xr[3];
#pragma unroll
    for (int k = 0; k < 6; ++k) {      // cross terms J_{i,4..9}
        T0 += sflip(xr[13 + k], lb[k]);
        T1 += sflip(xr[21 + k], lb[k]);
        T2 += sflip(xr[28 + k], lb[k]);
        T3 += sflip(xr[34 + k], lb[k]);
    }
    const float J01 = xr[10], J02 = xr[11], J03 = xr[12];
    const float J12 = xr[19], J13 = xr[20], J23 = xr[27];

    float expo[16];
#pragma unroll
    for (int r = 0; r < 16; ++r) {
        const unsigned b0 = (r >> 3) & 1u, b1 = (r >> 2) & 1u,
                       b2 = (r >> 1) & 1u, b3 = r & 1u;
        float e = L;
        e += sflip(T0, b0);       e += sflip(T1, b1);
        e += sflip(T2, b2);       e += sflip(T3, b3);
        e += sflip(J01, b0 ^ b1); e += sflip(J02, b0 ^ b2); e += sflip(J03, b0 ^ b3);
        e += sflip(J12, b1 ^ b2); e += sflip(J13, b1 ^ b3); e += sflip(J23, b2 ^ b3);
        expo[r] = e;
    }

    // ---- simulate BOTH circuits in this wave (a = actor, b = critic) ----
    v2f a[16], b[16];
#pragma unroll
    for (int r = 0; r < 16; ++r) {
        a[r] = (v2f){0.03125f, 0.f};   // 1/sqrt(1024)
        b[r] = (v2f){0.03125f, 0.f};
    }

#pragma unroll 1                       // one layer per iteration: fits I-cache
    for (int l = 0; l < NL; ++l) {
        const float mA = -0.5f * isa[l];
        const float mC = -0.5f * isc[l];
        float sA, cA, sC, cC;
        __sincosf(0.5f * wa[l], &sA, &cA);
        __sincosf(0.5f * wc[l], &sC, &cC);
        const v2f scA = {sA, cA}, scC = {sC, cC};

        // diagonal phase (packed complex mul) -- a and b interleaved
#pragma unroll
        for (int r = 0; r < 16; ++r) {
            float sn, cs;
            __sincosf(mA * expo[r], &sn, &cs);
            a[r] = cmul_pk(a[r], (v2f){sn, cs});
            __sincosf(mC * expo[r], &sn, &cs);
            b[r] = cmul_pk(b[r], (v2f){sn, cs});
        }

        // qubits 0..3: register butterflies (r-bit masks 8,4,2,1)
#pragma unroll
        for (int g = 0; g < 4; ++g) {
            const int qm = 8 >> g;
#pragma unroll
            for (int r = 0; r < 16; ++r)
                if (!(r & qm)) {
                    const v2f lo = a[r], hi = a[r | qm];
                    a[r]      = rotg_pk(lo, hi, scA);
                    a[r | qm] = rotg_pk(hi, lo, scA);
                    const v2f lo2 = b[r], hi2 = b[r | qm];
                    b[r]      = rotg_pk(lo2, hi2, scC);
                    b[r | qm] = rotg_pk(hi2, lo2, scC);
                }
        }

        // qubit 4: lane^32 via paired permlane32_swap
#pragma unroll
        for (int r = 0; r < 16; r += 2) {
            gate_pl<true>(a[r], a[r + 1], scA);
            gate_pl<true>(b[r], b[r + 1], scC);
        }
        // qubit 5: lane^16 via paired permlane16_swap
#pragma unroll
        for (int r = 0; r < 16; r += 2) {
            gate_pl<false>(a[r], a[r + 1], scA);
            gate_pl<false>(b[r], b[r + 1], scC);
        }
        // qubit 6: lane^8 via DPP row_ror:8
#pragma unroll
        for (int r = 0; r < 16; ++r) {
            const v2f oa = {dppx<0x128>(a[r].x), dppx<0x128>(a[r].y)};
            a[r] = rotg_pk(a[r], oa, scA);
            const v2f ob = {dppx<0x128>(b[r].x), dppx<0x128>(b[r].y)};
            b[r] = rotg_pk(b[r], ob, scC);
        }
        // qubit 7: lane^4 via composed DPP (^7 then ^3)
#pragma unroll
        for (int r = 0; r < 16; ++r) {
            const v2f oa = {dpp_x4(a[r].x), dpp_x4(a[r].y)};
            a[r] = rotg_pk(a[r], oa, scA);
            const v2f ob = {dpp_x4(b[r].x), dpp_x4(b[r].y)};
            b[r] = rotg_pk(b[r], ob, scC);
        }
        // qubit 8: lane^2 via quad_perm
#pragma unroll
        for (int r = 0; r < 16; ++r) {
            const v2f oa = {dppx<0x4E>(a[r].x), dppx<0x4E>(a[r].y)};
            a[r] = rotg_pk(a[r], oa, scA);
            const v2f ob = {dppx<0x4E>(b[r].x), dppx<0x4E>(b[r].y)};
            b[r] = rotg_pk(b[r], ob, scC);
        }
        // qubit 9: lane^1 via quad_perm
#pragma unroll
        for (int r = 0; r < 16; ++r) {
            const v2f oa = {dppx<0xB1>(a[r].x), dppx<0xB1>(a[r].y)};
            a[r] = rotg_pk(a[r], oa, scA);
            const v2f ob = {dppx<0xB1>(b[r].x), dppx<0xB1>(b[r].y)};
            b[r] = rotg_pk(b[r], ob, scC);
        }
    }

    // ---- probabilities & expectation values ----
    float pa[16], pb[16];
#pragma unroll
    for (int r = 0; r < 16; ++r) {
        pa[r] = a[r].x * a[r].x + a[r].y * a[r].y;
        pb[r] = b[r].x * b[r].x + b[r].y * b[r].y;
    }
    float totA = 0.f;
#pragma unroll
    for (int r = 0; r < 16; ++r) totA += pa[r];

    // actor: all 10 <Z_q>
    float v[10];
#pragma unroll
    for (int q = 0; q < 4; ++q) {
        const int qm = 8 >> q;
        float acc = 0.f;
#pragma unroll
        for (int r = 0; r < 16; ++r) acc += (r & qm) ? -pa[r] : pa[r];
        v[q] = acc;
    }
#pragma unroll
    for (int k = 0; k < 6; ++k) v[4 + k] = sflip(totA, lb[k]);
#pragma unroll
    for (int q = 0; q < 10; ++q) v[q] = wave_sum(v[q]);

    // critic: only <Z_0> (r-bit 3)
    float v0 = 0.f;
#pragma unroll
    for (int r = 0; r < 16; ++r) v0 += (r & 8) ? -pb[r] : pb[r];
    v0 = wave_sum(v0);

    // epilogue redundantly on all lanes (no divergence), lane 0 stores
    float logits[10], mx = -1e30f;
#pragma unroll
    for (int q = 0; q < 10; ++q) {
        logits[q] = v[q] * osa[q];
        mx = fmaxf(mx, logits[q]);
    }
    float se = 0.f;
#pragma unroll
    for (int q = 0; q < 10; ++q) se += __expf(logits[q] - mx);
    const float lse = __logf(se) + mx;
    float ent = 0.f;
#pragma unroll
    for (int q = 0; q < 10; ++q) {
        const float lp = logits[q] - lse;
        ent -= __expf(lp) * lp;
    }
    if (lane == 0) {
        const int act = action[elem];
        out[elem * 3 + 0] = logits[act] - lse;
        out[elem * 3 + 1] = ent;
        out[elem * 3 + 2] = v0 * osc[0];
    }
}

extern "C" void kernel_launch(void* const* d_in, const int* in_sizes, int n_in,
                              void* d_out, int out_size, void* d_ws, size_t ws_size,
                              hipStream_t stream) {
    const float* x      = (const float*)d_in[0];
    const float* isa    = (const float*)d_in[1];
    const float* wa     = (const float*)d_in[2];
    const float* osa    = (const float*)d_in[3];
    const float* isc    = (const float*)d_in[4];
    const float* wc     = (const float*)d_in[5];
    const float* osc    = (const float*)d_in[6];
    const int*   action = (const int*)d_in[7];
    float*       out    = (float*)d_out;

    const int B = in_sizes[7];
    // one wave per element (both circuits in-wave); 2 elems per 128-thread block
    ppo_quantum_kernel<<<B / 2, 128, 0, stream>>>(x, isa, wa, osa, isc, wc, osc,
                                                  action, out);
}

// Round 15
// 31.978 us; speedup vs baseline: 1.1891x; 1.1344x over previous
//
#include <hip/hip_runtime.h>

#define NL 5

typedef float v2f __attribute__((ext_vector_type(2)));

// flip sign of v iff bit==1
__device__ __forceinline__ float sflip(float v, unsigned bit) {
    return __uint_as_float(__float_as_uint(v) ^ (bit << 31));
}

// ---- packed FP32 complex helpers (VOP3P, 2 FLOP/lane/instr) ----
// RX butterfly: new = (c*me.x + s*o.y, c*me.y - s*o.x), sc = (s, c)
__device__ __forceinline__ v2f rotg_pk(v2f me, v2f o, v2f sc) {
    v2f t, r;
    // t.lo = s*o.hi ; t.hi = -s*o.lo
    asm("v_pk_mul_f32 %0, %1, %2 op_sel:[0,1] op_sel_hi:[0,0] neg_hi:[1,0]"
        : "=v"(t) : "v"(sc), "v"(o));
    // r.lo = c*me.lo + t.lo ; r.hi = c*me.hi + t.hi
    asm("v_pk_fma_f32 %0, %1, %2, %3 op_sel:[1,0,0] op_sel_hi:[1,1,1]"
        : "=v"(r) : "v"(sc), "v"(me), "v"(t));
    return r;
}
// complex phase: new = (x*cs - y*sn, x*sn + y*cs), sc = (sn, cs)
__device__ __forceinline__ v2f cmul_pk(v2f a, v2f sc) {
    v2f t, r;
    // t.lo = -sn*a.hi ; t.hi = sn*a.lo
    asm("v_pk_mul_f32 %0, %1, %2 op_sel:[0,1] op_sel_hi:[0,0] neg_lo:[1,0]"
        : "=v"(t) : "v"(sc), "v"(a));
    // r.lo = cs*a.lo + t.lo ; r.hi = cs*a.hi + t.hi
    asm("v_pk_fma_f32 %0, %1, %2, %3 op_sel:[1,0,0] op_sel_hi:[1,1,1]"
        : "=v"(r) : "v"(sc), "v"(a), "v"(t));
    return r;
}

// DPP cross-lane on the VALU pipe.
//   0xB1 = quad_perm [1,0,3,2]  -> lane^1
//   0x4E = quad_perm [2,3,0,1]  -> lane^2
//   0x1B = quad_perm [3,2,1,0]  -> lane^3
//   0x141 = row_half_mirror     -> lane^7 (within 8)
//   0x128 = row_ror:8           -> lane^8 (xor 8 within a 16-row)
template <int CTRL>
__device__ __forceinline__ float dppx(float v) {
    return __int_as_float(__builtin_amdgcn_update_dpp(
        0, __float_as_int(v), CTRL, 0xF, 0xF, true));
}
// data from lane^4 = (^7) then (^3)
__device__ __forceinline__ float dpp_x4(float v) { return dppx<0x1B>(dppx<0x141>(v)); }

// ---- permlane pair-swap (inline asm, "+v" tied in/out) ----
// After the swap each lane holds both xor-MASK partners of one logical
// register -> butterfly is lane-local; swap again to restore. (HW-verified
// correct in R11: absmax 6.1e-5.)
template <bool IS32>
__device__ __forceinline__ void swap_pair(float &X, float &Y) {
    if (IS32)
        asm("v_permlane32_swap_b32 %0, %1" : "+v"(X), "+v"(Y));
    else
        asm("v_permlane16_swap_b32 %0, %1" : "+v"(X), "+v"(Y));
}
// RX gate for lane-mask 32 (IS32) or 16 on a register pair (A,B)
template <bool IS32>
__device__ __forceinline__ void gate_pl(v2f &A, v2f &B, v2f sc) {
    float ax = A.x, ay = A.y, bx = B.x, by = B.y;
    swap_pair<IS32>(ax, bx);
    swap_pair<IS32>(ay, by);
    const v2f u = {ax, ay}, v = {bx, by};
    v2f nu = rotg_pk(u, v, sc);
    v2f nv = rotg_pk(v, u, sc);
    ax = nu.x; ay = nu.y; bx = nv.x; by = nv.y;
    swap_pair<IS32>(ax, bx);
    swap_pair<IS32>(ay, by);
    A = (v2f){ax, ay};
    B = (v2f){bx, by};
}

// all-lanes butterfly sum across the 64-lane wave (one-shot)
__device__ __forceinline__ float wave_sum(float v) {
    v += dppx<0xB1>(v);
    v += dppx<0x4E>(v);
    v += dpp_x4(v);
    v += dppx<0x128>(v);
    v += __shfl_xor(v, 16);
    v += __shfl_xor(v, 32);
    return v;
}

__global__ __launch_bounds__(128, 4)
void ppo_quantum_kernel(const float* __restrict__ x,        // (B,55)
                        const float* __restrict__ isa,      // (5,)
                        const float* __restrict__ wa,       // (5,)
                        const float* __restrict__ osa,      // (10,)
                        const float* __restrict__ isc,      // (5,)
                        const float* __restrict__ wc,       // (5,)
                        const float* __restrict__ osc,      // (1,)
                        const int*   __restrict__ action,   // (B,)
                        float* __restrict__ out)            // (B,3)
{
    const int t    = threadIdx.x;      // 128 threads = 2 INDEPENDENT waves
    const int circ = t >> 6;           // wave 0 = actor, wave 1 = critic (same elem)
    const int lane = t & 63;
    const int elem = blockIdx.x;
    const float* __restrict__ xr = x + elem * 55;   // wave-uniform -> scalar loads

    // amplitude index d = (r<<6) | lane, r = 0..15
    // qubit q acts on d-bit (9-q): q0..q3 -> r bits 3..0 (register gates)
    //                              q4..q9 -> lane bits 5..0 (masks 32,16,8,4,2,1)
    unsigned lb[6];                    // lane bit of qubit 4+k
#pragma unroll
    for (int k = 0; k < 6; ++k) lb[k] = (lane >> (5 - k)) & 1u;

    // ---- expo decomposition ----
    float L = 0.f;                     // lane-only: singles 4..9 + pairs among them
#pragma unroll
    for (int k = 0; k < 6; ++k) L += sflip(xr[4 + k], lb[k]);
    {
        int p = 40;                    // J_ij for i,j in 4..9 at x[40..54]
#pragma unroll
        for (int i = 0; i < 6; ++i)
#pragma unroll
            for (int j = i + 1; j < 6; ++j)
                L += sflip(xr[p++], lb[i] ^ lb[j]);
    }
    float T0 = xr[0], T1 = xr[1], T2 = xr[2], T3 = xr[3];
#pragma unroll
    for (int k = 0; k < 6; ++k) {      // cross terms J_{i,4..9}
        T0 += sflip(xr[13 + k], lb[k]);
        T1 += sflip(xr[21 + k], lb[k]);
        T2 += sflip(xr[28 + k], lb[k]);
        T3 += sflip(xr[34 + k], lb[k]);
    }
    const float J01 = xr[10], J02 = xr[11], J03 = xr[12];
    const float J12 = xr[19], J13 = xr[20], J23 = xr[27];

    float expo[16];
#pragma unroll
    for (int r = 0; r < 16; ++r) {
        const unsigned b0 = (r >> 3) & 1u, b1 = (r >> 2) & 1u,
                       b2 = (r >> 1) & 1u, b3 = r & 1u;
        float e = L;
        e += sflip(T0, b0);       e += sflip(T1, b1);
        e += sflip(T2, b2);       e += sflip(T3, b3);
        e += sflip(J01, b0 ^ b1); e += sflip(J02, b0 ^ b2); e += sflip(J03, b0 ^ b3);
        e += sflip(J12, b1 ^ b2); e += sflip(J13, b1 ^ b3); e += sflip(J23, b2 ^ b3);
        expo[r] = e;
    }

    // ---- simulate this wave's circuit ----
    const float* iscale = circ ? isc : isa;
    const float* wts    = circ ? wc  : wa;

    v2f a[16];
#pragma unroll
    for (int r = 0; r < 16; ++r) a[r] = (v2f){0.03125f, 0.f};  // 1/sqrt(1024)

    // cached diagonal phases: recomputed only when input_scaling[l] changes
    v2f ph[16];
    float s_cache = __uint_as_float(0x7fc00000u);   // NaN: always != first s_l

#pragma unroll 1                       // one layer per iteration
    for (int l = 0; l < NL; ++l) {
        const float sl = iscale[l];
        float c, s;
        __sincosf(0.5f * wts[l], &s, &c);
        const v2f sc = {s, c};

        if (sl != s_cache) {           // wave-uniform scalar branch
            s_cache = sl;
            const float m = -0.5f * sl;
#pragma unroll
            for (int r = 0; r < 16; ++r) {
                float sn, cs;
                __sincosf(m * expo[r], &sn, &cs);
                ph[r] = (v2f){sn, cs};
            }
        }

        // diagonal phase (packed complex mul, cached phases)
#pragma unroll
        for (int r = 0; r < 16; ++r) a[r] = cmul_pk(a[r], ph[r]);

        // qubit 0 (r-mask 8) always applied
#pragma unroll
        for (int r = 0; r < 8; ++r) {
            const v2f lo = a[r], hi = a[r | 8];
            a[r]     = rotg_pk(lo, hi, sc);
            a[r | 8] = rotg_pk(hi, lo, sc);
        }

        // critic's final layer: only qubit 0 affects <Z_0>; RX on q!=0 is
        // norm-preserving within each z0 sector (exact identity) -> skip.
        const bool full = (circ == 0) || (l < NL - 1);
        if (full) {
            // qubits 1..3: register butterflies (r-bit masks 4,2,1)
#pragma unroll
            for (int g = 0; g < 3; ++g) {
                const int qm = 4 >> g;
#pragma unroll
                for (int r = 0; r < 16; ++r)
                    if (!(r & qm)) {
                        const v2f lo = a[r], hi = a[r | qm];
                        a[r]      = rotg_pk(lo, hi, sc);
                        a[r | qm] = rotg_pk(hi, lo, sc);
                    }
            }
            // qubit 4: lane^32 via paired permlane32_swap
#pragma unroll
            for (int r = 0; r < 16; r += 2) gate_pl<true>(a[r], a[r + 1], sc);
            // qubit 5: lane^16 via paired permlane16_swap
#pragma unroll
            for (int r = 0; r < 16; r += 2) gate_pl<false>(a[r], a[r + 1], sc);
            // qubit 6: lane^8 via DPP row_ror:8
#pragma unroll
            for (int r = 0; r < 16; ++r) {
                const v2f o = {dppx<0x128>(a[r].x), dppx<0x128>(a[r].y)};
                a[r] = rotg_pk(a[r], o, sc);
            }
            // qubit 7: lane^4 via composed DPP (^7 then ^3)
#pragma unroll
            for (int r = 0; r < 16; ++r) {
                const v2f o = {dpp_x4(a[r].x), dpp_x4(a[r].y)};
                a[r] = rotg_pk(a[r], o, sc);
            }
            // qubit 8: lane^2 via quad_perm
#pragma unroll
            for (int r = 0; r < 16; ++r) {
                const v2f o = {dppx<0x4E>(a[r].x), dppx<0x4E>(a[r].y)};
                a[r] = rotg_pk(a[r], o, sc);
            }
            // qubit 9: lane^1 via quad_perm
#pragma unroll
            for (int r = 0; r < 16; ++r) {
                const v2f o = {dppx<0xB1>(a[r].x), dppx<0xB1>(a[r].y)};
                a[r] = rotg_pk(a[r], o, sc);
            }
        }
    }

    // ---- probabilities & expectation values ----
    float p[16];
#pragma unroll
    for (int r = 0; r < 16; ++r) p[r] = a[r].x * a[r].x + a[r].y * a[r].y;
    float tot = 0.f;
#pragma unroll
    for (int r = 0; r < 16; ++r) tot += p[r];

    if (circ == 0) {
        // actor: all 10 <Z_q>
        float v[10];
#pragma unroll
        for (int q = 0; q < 4; ++q) {
            const int qm = 8 >> q;
            float acc = 0.f;
#pragma unroll
            for (int r = 0; r < 16; ++r) acc += (r & qm) ? -p[r] : p[r];
            v[q] = acc;
        }
#pragma unroll
        for (int k = 0; k < 6; ++k) v[4 + k] = sflip(tot, lb[k]);
#pragma unroll
        for (int q = 0; q < 10; ++q) v[q] = wave_sum(v[q]);

        // epilogue redundantly on all lanes (no divergence), lane 0 stores
        float logits[10], mx = -1e30f;
#pragma unroll
        for (int q = 0; q < 10; ++q) {
            logits[q] = v[q] * osa[q];
            mx = fmaxf(mx, logits[q]);
        }
        float se = 0.f;
#pragma unroll
        for (int q = 0; q < 10; ++q) se += __expf(logits[q] - mx);
        const float lse = __logf(se) + mx;
        float ent = 0.f;
#pragma unroll
        for (int q = 0; q < 10; ++q) {
            const float lp = logits[q] - lse;
            ent -= __expf(lp) * lp;
        }
        if (lane == 0) {
            const int act = action[elem];
            out[elem * 3 + 0] = logits[act] - lse;
            out[elem * 3 + 1] = ent;
        }
    } else {
        // critic: only <Z_0> (r-bit 3)
        float v0 = 0.f;
#pragma unroll
        for (int r = 0; r < 16; ++r) v0 += (r & 8) ? -p[r] : p[r];
        v0 = wave_sum(v0);
        if (lane == 0) out[elem * 3 + 2] = v0 * osc[0];
    }
}

extern "C" void kernel_launch(void* const* d_in, const int* in_sizes, int n_in,
                              void* d_out, int out_size, void* d_ws, size_t ws_size,
                              hipStream_t stream) {
    const float* x      = (const float*)d_in[0];
    const float* isa    = (const float*)d_in[1];
    const float* wa     = (const float*)d_in[2];
    const float* osa    = (const float*)d_in[3];
    const float* isc    = (const float*)d_in[4];
    const float* wc     = (const float*)d_in[5];
    const float* osc    = (const float*)d_in[6];
    const int*   action = (const int*)d_in[7];
    float*       out    = (float*)d_out;

    const int B = in_sizes[7];
    // one block per element: wave 0 = actor, wave 1 = critic; no barriers, no LDS
    ppo_quantum_kernel<<<B, 128, 0, stream>>>(x, isa, wa, osa, isc, wc, osc,
                                              action, out);
}

// Round 17
// 27.985 us; speedup vs baseline: 1.3587x; 1.1427x over previous
//
#include <hip/hip_runtime.h>

#define NL 5

typedef _Float16 h2 __attribute__((ext_vector_type(2)));
typedef __fp16   fp16v2 __attribute__((ext_vector_type(2)));

// pack two f32 -> f16x2 (round-to-zero), one v_cvt_pkrtz_f16_f32
__device__ __forceinline__ h2 pkrtz(float lo, float hi) {
    return __builtin_bit_cast(h2, __builtin_amdgcn_cvt_pkrtz(lo, hi));
}

// flip sign of v iff bit==1
__device__ __forceinline__ float sflip(float v, unsigned bit) {
    return __uint_as_float(__float_as_uint(v) ^ (bit << 31));
}

// ---- packed f16 complex helpers: one amplitude = one VGPR (x=lo, y=hi) ----
// RX butterfly: new = (c*x + s*o.y, c*y - s*o.x), sc = (s, c)
__device__ __forceinline__ h2 rotg16(h2 me, h2 o, h2 sc) {
    h2 t, r;
    // t.lo = s*o.hi ; t.hi = -s*o.lo
    asm("v_pk_mul_f16 %0, %1, %2 op_sel:[0,1] op_sel_hi:[0,0] neg_hi:[1,0]"
        : "=v"(t) : "v"(sc), "v"(o));
    // r.lo = c*me.lo + t.lo ; r.hi = c*me.hi + t.hi
    asm("v_pk_fma_f16 %0, %1, %2, %3 op_sel:[1,0,0] op_sel_hi:[1,1,1]"
        : "=v"(r) : "v"(sc), "v"(me), "v"(t));
    return r;
}
// complex phase: new = (x*cs - y*sn, x*sn + y*cs), ph = (sn, cs)
__device__ __forceinline__ h2 cmul16(h2 a, h2 ph) {
    h2 t, r;
    // t.lo = -sn*a.hi ; t.hi = sn*a.lo
    asm("v_pk_mul_f16 %0, %1, %2 op_sel:[0,1] op_sel_hi:[0,0] neg_lo:[1,0]"
        : "=v"(t) : "v"(ph), "v"(a));
    // r.lo = cs*a.lo + t.lo ; r.hi = cs*a.hi + t.hi
    asm("v_pk_fma_f16 %0, %1, %2, %3 op_sel:[1,0,0] op_sel_hi:[1,1,1]"
        : "=v"(r) : "v"(ph), "v"(a), "v"(t));
    return r;
}

// DPP cross-lane (whole f16x2 amplitude in one mov).
//   0xB1 quad_perm -> lane^1 ; 0x4E -> lane^2 ; 0x1B -> lane^3
//   0x141 row_half_mirror -> lane^7 ; 0x128 row_ror:8 -> lane^8
template <int CTRL>
__device__ __forceinline__ float dppx(float v) {
    return __int_as_float(__builtin_amdgcn_update_dpp(
        0, __float_as_int(v), CTRL, 0xF, 0xF, true));
}
template <int CTRL>
__device__ __forceinline__ h2 dpph(h2 v) {
    return __builtin_bit_cast(h2, dppx<CTRL>(__builtin_bit_cast(float, v)));
}
__device__ __forceinline__ h2 dpph_x4(h2 v) { return dpph<0x1B>(dpph<0x141>(v)); }
__device__ __forceinline__ float dpp_x4(float v) { return dppx<0x1B>(dppx<0x141>(v)); }

// ---- permlane pair-swap on whole amplitudes (1 instr per reg pair) ----
template <bool IS32>
__device__ __forceinline__ void swap16(h2 &X, h2 &Y) {
    if (IS32)
        asm("v_permlane32_swap_b32 %0, %1" : "+v"(X), "+v"(Y));
    else
        asm("v_permlane16_swap_b32 %0, %1" : "+v"(X), "+v"(Y));
}
// RX gate for lane-mask 32 (IS32) or 16 on amplitude pair (A,B): swap in,
// lane-local butterfly, swap back. (Same derivation HW-verified in R11.)
template <bool IS32>
__device__ __forceinline__ void gate_pl16(h2 &A, h2 &B, h2 sc) {
    swap16<IS32>(A, B);
    const h2 u = A, v = B;
    A = rotg16(u, v, sc);
    B = rotg16(v, u, sc);
    swap16<IS32>(A, B);
}

// all-lanes butterfly sum across the 64-lane wave (f32, one-shot)
__device__ __forceinline__ float wave_sum(float v) {
    v += dppx<0xB1>(v);
    v += dppx<0x4E>(v);
    v += dpp_x4(v);
    v += dppx<0x128>(v);
    v += __shfl_xor(v, 16);
    v += __shfl_xor(v, 32);
    return v;
}

__global__ __launch_bounds__(128, 4)
void ppo_quantum_kernel(const float* __restrict__ x,        // (B,55)
                        const float* __restrict__ isa,      // (5,)
                        const float* __restrict__ wa,       // (5,)
                        const float* __restrict__ osa,      // (10,)
                        const float* __restrict__ isc,      // (5,)
                        const float* __restrict__ wc,       // (5,)
                        const float* __restrict__ osc,      // (1,)
                        const int*   __restrict__ action,   // (B,)
                        float* __restrict__ out)            // (B,3)
{
    const int t    = threadIdx.x;      // 128 threads = 2 INDEPENDENT waves
    const int circ = t >> 6;           // wave 0 = actor, wave 1 = critic (same elem)
    const int lane = t & 63;
    const int elem = blockIdx.x;
    const float* __restrict__ xr = x + elem * 55;   // wave-uniform -> scalar loads

    // amplitude index d = (r<<6) | lane, r = 0..15
    // qubit q acts on d-bit (9-q): q0..q3 -> r bits 3..0 (register gates)
    //                              q4..q9 -> lane bits 5..0 (masks 32,16,8,4,2,1)
    unsigned lb[6];                    // lane bit of qubit 4+k
#pragma unroll
    for (int k = 0; k < 6; ++k) lb[k] = (lane >> (5 - k)) & 1u;

    // ---- expo decomposition ----
    float L = 0.f;                     // lane-only: singles 4..9 + pairs among them
#pragma unroll
    for (int k = 0; k < 6; ++k) L += sflip(xr[4 + k], lb[k]);
    {
        int p = 40;                    // J_ij for i,j in 4..9 at x[40..54]
#pragma unroll
        for (int i = 0; i < 6; ++i)
#pragma unroll
            for (int j = i + 1; j < 6; ++j)
                L += sflip(xr[p++], lb[i] ^ lb[j]);
    }
    float T0 = xr[0], T1 = xr[1], T2 = xr[2], T3 = xr[3];
#pragma unroll
    for (int k = 0; k < 6; ++k) {      // cross terms J_{i,4..9}
        T0 += sflip(xr[13 + k], lb[k]);
        T1 += sflip(xr[21 + k], lb[k]);
        T2 += sflip(xr[28 + k], lb[k]);
        T3 += sflip(xr[34 + k], lb[k]);
    }
    const float J01 = xr[10], J02 = xr[11], J03 = xr[12];
    const float J12 = xr[19], J13 = xr[20], J23 = xr[27];

    float expo[16];
#pragma unroll
    for (int r = 0; r < 16; ++r) {
        const unsigned b0 = (r >> 3) & 1u, b1 = (r >> 2) & 1u,
                       b2 = (r >> 1) & 1u, b3 = r & 1u;
        float e = L;
        e += sflip(T0, b0);       e += sflip(T1, b1);
        e += sflip(T2, b2);       e += sflip(T3, b3);
        e += sflip(J01, b0 ^ b1); e += sflip(J02, b0 ^ b2); e += sflip(J03, b0 ^ b3);
        e += sflip(J12, b1 ^ b2); e += sflip(J13, b1 ^ b3); e += sflip(J23, b2 ^ b3);
        expo[r] = e;
    }

    // ---- simulate this wave's circuit (f16x2 amplitudes) ----
    const float* iscale = circ ? isc : isa;
    const float* wts    = circ ? wc  : wa;

    h2 a[16];
#pragma unroll
    for (int r = 0; r < 16; ++r) a[r] = (h2){(_Float16)0.03125f, (_Float16)0.f};

    // cached diagonal phases: recomputed only when input_scaling[l] changes
    h2 ph[16];
    float s_cache = __uint_as_float(0x7fc00000u);   // NaN: always != first s_l

#pragma unroll 1                       // one layer per iteration
    for (int l = 0; l < NL; ++l) {
        const float sl = iscale[l];
        float c, s;
        __sincosf(0.5f * wts[l], &s, &c);
        const h2 sc = pkrtz(s, c);

        if (sl != s_cache) {           // wave-uniform scalar branch
            s_cache = sl;
            const float m = -0.5f * sl;
#pragma unroll
            for (int r = 0; r < 16; ++r) {
                float sn, cs;
                __sincosf(m * expo[r], &sn, &cs);
                ph[r] = pkrtz(sn, cs);
            }
        }

        // diagonal phase (packed complex mul, cached phases)
#pragma unroll
        for (int r = 0; r < 16; ++r) a[r] = cmul16(a[r], ph[r]);

        // qubit 0 (r-mask 8) always applied
#pragma unroll
        for (int r = 0; r < 8; ++r) {
            const h2 lo = a[r], hi = a[r | 8];
            a[r]     = rotg16(lo, hi, sc);
            a[r | 8] = rotg16(hi, lo, sc);
        }

        // critic's final layer: only qubit 0 affects <Z_0>; RX on q!=0 is
        // norm-preserving within each z0 sector (exact identity) -> skip.
        const bool full = (circ == 0) || (l < NL - 1);
        if (full) {
            // qubits 1..3: register butterflies (r-bit masks 4,2,1)
#pragma unroll
            for (int g = 0; g < 3; ++g) {
                const int qm = 4 >> g;
#pragma unroll
                for (int r = 0; r < 16; ++r)
                    if (!(r & qm)) {
                        const h2 lo = a[r], hi = a[r | qm];
                        a[r]      = rotg16(lo, hi, sc);
                        a[r | qm] = rotg16(hi, lo, sc);
                    }
            }
            // qubit 4: lane^32 via paired permlane32_swap
#pragma unroll
            for (int r = 0; r < 16; r += 2) gate_pl16<true>(a[r], a[r + 1], sc);
            // qubit 5: lane^16 via paired permlane16_swap
#pragma unroll
            for (int r = 0; r < 16; r += 2) gate_pl16<false>(a[r], a[r + 1], sc);
            // qubit 6: lane^8 via DPP row_ror:8
#pragma unroll
            for (int r = 0; r < 16; ++r)
                a[r] = rotg16(a[r], dpph<0x128>(a[r]), sc);
            // qubit 7: lane^4 via composed DPP (^7 then ^3)
#pragma unroll
            for (int r = 0; r < 16; ++r)
                a[r] = rotg16(a[r], dpph_x4(a[r]), sc);
            // qubit 8: lane^2 via quad_perm
#pragma unroll
            for (int r = 0; r < 16; ++r)
                a[r] = rotg16(a[r], dpph<0x4E>(a[r]), sc);
            // qubit 9: lane^1 via quad_perm
#pragma unroll
            for (int r = 0; r < 16; ++r)
                a[r] = rotg16(a[r], dpph<0xB1>(a[r]), sc);
        }
    }

    // ---- probabilities (f32) & expectation values ----
    float p[16];
#pragma unroll
    for (int r = 0; r < 16; ++r) {
        const float ax = (float)a[r].x, ay = (float)a[r].y;
        p[r] = ax * ax + ay * ay;
    }
    float tot = 0.f;
#pragma unroll
    for (int r = 0; r < 16; ++r) tot += p[r];

    if (circ == 0) {
        // actor: all 10 <Z_q>
        float v[10];
#pragma unroll
        for (int q = 0; q < 4; ++q) {
            const int qm = 8 >> q;
            float acc = 0.f;
#pragma unroll
            for (int r = 0; r < 16; ++r) acc += (r & qm) ? -p[r] : p[r];
            v[q] = acc;
        }
#pragma unroll
        for (int k = 0; k < 6; ++k) v[4 + k] = sflip(tot, lb[k]);
#pragma unroll
        for (int q = 0; q < 10; ++q) v[q] = wave_sum(v[q]);

        // epilogue redundantly on all lanes (no divergence), lane 0 stores
        float logits[10], mx = -1e30f;
#pragma unroll
        for (int q = 0; q < 10; ++q) {
            logits[q] = v[q] * osa[q];
            mx = fmaxf(mx, logits[q]);
        }
        float se = 0.f;
#pragma unroll
        for (int q = 0; q < 10; ++q) se += __expf(logits[q] - mx);
        const float lse = __logf(se) + mx;
        float ent = 0.f;
#pragma unroll
        for (int q = 0; q < 10; ++q) {
            const float lp = logits[q] - lse;
            ent -= __expf(lp) * lp;
        }
        if (lane == 0) {
            const int act = action[elem];
            out[elem * 3 + 0] = logits[act] - lse;
            out[elem * 3 + 1] = ent;
        }
    } else {
        // critic: only <Z_0> (r-bit 3)
        float v0 = 0.f;
#pragma unroll
        for (int r = 0; r < 16; ++r) v0 += (r & 8) ? -p[r] : p[r];
        v0 = wave_sum(v0);
        if (lane == 0) out[elem * 3 + 2] = v0 * osc[0];
    }
}

extern "C" void kernel_launch(void* const* d_in, const int* in_sizes, int n_in,
                              void* d_out, int out_size, void* d_ws, size_t ws_size,
                              hipStream_t stream) {
    const float* x      = (const float*)d_in[0];
    const float* isa    = (const float*)d_in[1];
    const float* wa     = (const float*)d_in[2];
    const float* osa    = (const float*)d_in[3];
    const float* isc    = (const float*)d_in[4];
    const float* wc     = (const float*)d_in[5];
    const float* osc    = (const float*)d_in[6];
    const int*   action = (const int*)d_in[7];
    float*       out    = (float*)d_out;

    const int B = in_sizes[7];
    // one block per element: wave 0 = actor, wave 1 = critic; no barriers, no LDS
    ppo_quantum_kernel<<<B, 128, 0, stream>>>(x, isa, wa, osa, isc, wc, osc,
                                              action, out);
}